// Round 3
// baseline (4343.654 us; speedup 1.0000x reference)
//
#include <hip/hip_runtime.h>
#include <stdint.h>

#define N_USERS 200000
#define N_ITEMS 200000
#define NTOT    400000
#define DD      64
#define NNZ     12800000

typedef unsigned short u16;
typedef float f4 __attribute__((ext_vector_type(4)));
typedef short s8 __attribute__((ext_vector_type(8)));   // 8 bf16 in 4 VGPRs

__device__ __forceinline__ float bf2f(u16 u){
  union { unsigned int i; float f; } x; x.i = ((unsigned int)u) << 16; return x.f;
}
__device__ __forceinline__ u16 f2bf(float f){
  unsigned int i = __float_as_uint(f);
  unsigned int r = (i + 0x7FFFu + ((i >> 16) & 1u)) >> 16;
  return (u16)r;
}

// ---------- init: ego(bf16) = concat(user,item); out[:,0:64] = fp32 copy ----------
__global__ __launch_bounds__(256) void k_init(const float* __restrict__ ue,
                                              const float* __restrict__ ie,
                                              u16* __restrict__ ego,
                                              float* __restrict__ out){
  int t = blockIdx.x * 256 + threadIdx.x;          // 0 .. NTOT*64
  float v = (t < N_USERS * DD) ? ue[t] : ie[t - N_USERS * DD];
  ego[t] = f2bf(v);
  int row = t >> 6, col = t & 63;
  out[row * 256 + col] = v;
}

// ---------- counting sort: histogram ----------
__global__ __launch_bounds__(256) void k_hist(const int* __restrict__ rows,
                                              int* __restrict__ cnt){
  int e = blockIdx.x * 256 + threadIdx.x;
  atomicAdd(&cnt[rows[e]], 1);
}

// ---------- scan step 1: per-256-block exclusive scan ----------
__global__ __launch_bounds__(256) void k_scan1(const int* __restrict__ cnt,
                                               int* __restrict__ off,
                                               int* __restrict__ bsum){
  __shared__ int s[256];
  int i = blockIdx.x * 256 + threadIdx.x;
  int v = (i < NTOT) ? cnt[i] : 0;
  s[threadIdx.x] = v;
  __syncthreads();
  #pragma unroll
  for (int d = 1; d < 256; d <<= 1){
    int t = (threadIdx.x >= d) ? s[threadIdx.x - d] : 0;
    __syncthreads();
    s[threadIdx.x] += t;
    __syncthreads();
  }
  int incl = s[threadIdx.x];
  if (i < NTOT) off[i] = incl - v;
  if (threadIdx.x == 255) bsum[blockIdx.x] = incl;
}

// ---------- scan step 2: single-block scan of block sums (exclusive) ----------
__global__ __launch_bounds__(256) void k_scan2(int* __restrict__ bsum, int nb){
  __shared__ int s[256];
  __shared__ int carry_s;
  if (threadIdx.x == 0) carry_s = 0;
  __syncthreads();
  for (int base = 0; base < nb; base += 256){
    int i = base + threadIdx.x;
    int v = (i < nb) ? bsum[i] : 0;
    s[threadIdx.x] = v;
    __syncthreads();
    #pragma unroll
    for (int d = 1; d < 256; d <<= 1){
      int t = (threadIdx.x >= d) ? s[threadIdx.x - d] : 0;
      __syncthreads();
      s[threadIdx.x] += t;
      __syncthreads();
    }
    int incl = s[threadIdx.x];
    int c = carry_s;
    __syncthreads();
    if (i < nb) bsum[i] = c + incl - v;
    if (threadIdx.x == 255) carry_s = c + incl;
    __syncthreads();
  }
}

// ---------- scan step 3: add block offsets; init cursor; off[N]=NNZ ----------
__global__ __launch_bounds__(256) void k_scan3(int* __restrict__ off,
                                               const int* __restrict__ bsum,
                                               int* __restrict__ cursor){
  int i = blockIdx.x * 256 + threadIdx.x;
  if (i < NTOT){
    int o = off[i] + bsum[i >> 8];
    off[i] = o;
    cursor[i] = o;
  }
  if (i == 0) off[NTOT] = NNZ;
}

// ---------- scatter edges into row-grouped order (val stays fp32) ----------
__global__ __launch_bounds__(256) void k_scatter(const int* __restrict__ rows,
                                                 const int* __restrict__ cols,
                                                 const float* __restrict__ vals,
                                                 int* __restrict__ cursor,
                                                 uint2* __restrict__ edges){
  int e = blockIdx.x * 256 + threadIdx.x;
  int r = rows[e];
  int pos = atomicAdd(&cursor[r], 1);
  edges[pos] = make_uint2((unsigned)cols[e], __float_as_uint(vals[e]));
}

// ---------- pull-SpMM: one wave per row, lane = column d ----------
__global__ __launch_bounds__(256) void k_spmm(const int* __restrict__ off,
                                              const uint2* __restrict__ edges,
                                              const u16* __restrict__ ego,
                                              u16* __restrict__ side){
  int wid  = (blockIdx.x * 256 + threadIdx.x) >> 6;   // row
  int lane = threadIdx.x & 63;
  int s0 = off[wid], s1 = off[wid + 1];
  float acc = 0.0f;
  int e = s0;
  for (; e + 1 < s1; e += 2){
    uint2 e0 = edges[e];
    uint2 e1 = edges[e + 1];
    float x0 = bf2f(ego[(unsigned)e0.x * 64u + lane]);
    float x1 = bf2f(ego[(unsigned)e1.x * 64u + lane]);
    acc += __uint_as_float(e0.y) * x0;
    acc += __uint_as_float(e1.y) * x1;
  }
  if (e < s1){
    uint2 e0 = edges[e];
    acc += __uint_as_float(e0.y) * bf2f(ego[(unsigned)e0.x * 64u + lane]);
  }
  side[wid * 64 + lane] = f2bf(acc);
}

// ---------- fused layer: GC + Bi GEMMs (MFMA), bias, leaky-relu, add, norm ----------
__global__ __launch_bounds__(256) void k_fused(const u16* __restrict__ side,
                                               const u16* __restrict__ ego_in,
                                               u16* __restrict__ ego_out,
                                               float* __restrict__ out,
                                               const float* __restrict__ gw,
                                               const float* __restrict__ gb,
                                               const float* __restrict__ bw,
                                               const float* __restrict__ bb,
                                               int layer){
  int lane = threadIdx.x & 63;
  int wave = threadIdx.x >> 6;
  int rowbase = blockIdx.x * 64 + wave * 16;
  int m = lane & 15, quad = lane >> 4;

  const float* gwL = gw + layer * 4096;
  const float* bwL = bw + layer * 4096;

  union F8 { s8 v; u16 h[8]; };

  // A fragments (A[m=lane&15][k=quad*8+j]): side and ego*side, rows rowbase..+15
  F8 as0, as1, ae0, ae1, ap0, ap1;
  int arow = (rowbase + m) * 64 + quad * 8;
  as0.v = *(const s8*)(side + arow);
  as1.v = *(const s8*)(side + arow + 32);
  ae0.v = *(const s8*)(ego_in + arow);
  ae1.v = *(const s8*)(ego_in + arow + 32);
  #pragma unroll
  for (int j = 0; j < 8; j++){
    ap0.h[j] = f2bf(bf2f(ae0.h[j]) * bf2f(as0.h[j]));
    ap1.h[j] = f2bf(bf2f(ae1.h[j]) * bf2f(as1.h[j]));
  }

  // B fragments: B[k][n] = W[n][k]; lane supplies n = lane&15, k = kb*32+quad*8+j
  // weights are fp32 -> convert to bf16 fragments
  F8 bg[4][2], bww[4][2];
  #pragma unroll
  for (int t = 0; t < 4; t++){
    #pragma unroll
    for (int kb = 0; kb < 2; kb++){
      int widx = (t * 16 + m) * 64 + kb * 32 + quad * 8;
      #pragma unroll
      for (int j = 0; j < 8; j++){
        bg[t][kb].h[j]  = f2bf(gwL[widx + j]);
        bww[t][kb].h[j] = f2bf(bwL[widx + j]);
      }
    }
  }

  f4 ag[4], ab[4];
  #pragma unroll
  for (int t = 0; t < 4; t++){
    ag[t] = (f4){0.f, 0.f, 0.f, 0.f};
    ab[t] = (f4){0.f, 0.f, 0.f, 0.f};
  }

  #pragma unroll
  for (int t = 0; t < 4; t++){
    ag[t] = __builtin_amdgcn_mfma_f32_16x16x32_bf16(as0.v, bg[t][0].v, ag[t], 0, 0, 0);
    ag[t] = __builtin_amdgcn_mfma_f32_16x16x32_bf16(as1.v, bg[t][1].v, ag[t], 0, 0, 0);
    ab[t] = __builtin_amdgcn_mfma_f32_16x16x32_bf16(ap0.v, bww[t][0].v, ab[t], 0, 0, 0);
    ab[t] = __builtin_amdgcn_mfma_f32_16x16x32_bf16(ap1.v, bww[t][1].v, ab[t], 0, 0, 0);
  }

  // epilogue: bias + leaky_relu(0.01) + add
  float ev[4][4];
  #pragma unroll
  for (int t = 0; t < 4; t++){
    float gcb = gb[layer * 64 + t * 16 + m];
    float bib = bb[layer * 64 + t * 16 + m];
    #pragma unroll
    for (int r = 0; r < 4; r++){
      float x = ag[t][r] + gcb; x = (x > 0.f) ? x : 0.01f * x;
      float y = ab[t][r] + bib; y = (y > 0.f) ? y : 0.01f * y;
      ev[t][r] = x + y;
    }
  }

  // row L2 norms: lane holds (row=quad*4+r, col=t*16+m); reduce over m (lane bits 0-3)
  float inv[4];
  #pragma unroll
  for (int r = 0; r < 4; r++){
    float p = 0.f;
    #pragma unroll
    for (int t = 0; t < 4; t++) p += ev[t][r] * ev[t][r];
    p += __shfl_xor(p, 1);
    p += __shfl_xor(p, 2);
    p += __shfl_xor(p, 4);
    p += __shfl_xor(p, 8);
    inv[r] = 1.0f / fmaxf(sqrtf(p), 1e-12f);
  }

  #pragma unroll
  for (int t = 0; t < 4; t++){
    #pragma unroll
    for (int r = 0; r < 4; r++){
      int row = rowbase + quad * 4 + r;
      int col = t * 16 + m;
      ego_out[row * 64 + col] = f2bf(ev[t][r]);                 // un-normalized ego (bf16)
      out[row * 256 + (layer + 1) * 64 + col] = ev[t][r] * inv[r];  // fp32 output
    }
  }
}

extern "C" void kernel_launch(void* const* d_in, const int* in_sizes, int n_in,
                              void* d_out, int out_size, void* d_ws, size_t ws_size,
                              hipStream_t stream) {
  const int*   rows = (const int*)d_in[0];
  const int*   cols = (const int*)d_in[1];
  const float* vals = (const float*)d_in[2];
  const float* ue   = (const float*)d_in[3];
  const float* ie   = (const float*)d_in[4];
  const float* gw   = (const float*)d_in[5];
  const float* gb   = (const float*)d_in[6];
  const float* bw   = (const float*)d_in[7];
  const float* bb   = (const float*)d_in[8];
  float* out = (float*)d_out;

  char* ws = (char*)d_ws;
  u16*   ego    = (u16*)(ws + 0);                       // 51,200,000 B
  u16*   side   = (u16*)(ws + 51200000);                // 51,200,000 B
  uint2* edges  = (uint2*)(ws + 102400000);             // 102,400,000 B
  int*   cnt    = (int*)(ws + 204800000);               // 1,600,000 B
  int*   off    = (int*)(ws + 206400000);               // 1,600,004 B
  int*   cursor = (int*)(ws + 208000256);               // 1,600,000 B
  int*   bsum   = (int*)(ws + 209600256);               // ~6,400 B

  hipMemsetAsync(cnt, 0, NTOT * sizeof(int), stream);

  k_init<<<(NTOT * DD) / 256, 256, 0, stream>>>(ue, ie, ego, out);
  k_hist<<<NNZ / 256, 256, 0, stream>>>(rows, cnt);
  k_scan1<<<(NTOT + 255) / 256, 256, 0, stream>>>(cnt, off, bsum);
  k_scan2<<<1, 256, 0, stream>>>(bsum, (NTOT + 255) / 256);
  k_scan3<<<(NTOT + 255) / 256, 256, 0, stream>>>(off, bsum, cursor);
  k_scatter<<<NNZ / 256, 256, 0, stream>>>(rows, cols, vals, cursor, edges);

  for (int l = 0; l < 3; l++){
    k_spmm<<<(NTOT * 64) / 256, 256, 0, stream>>>(off, edges, ego, side);
    k_fused<<<NTOT / 64, 256, 0, stream>>>(side, ego, ego, out,
                                           gw, gb, bw, bb, l);
  }
}